// Round 2
// baseline (778.114 us; speedup 1.0000x reference)
//
#include <hip/hip_runtime.h>

#define N_NODES 50000
#define N_EDGES 800000
#define IN_DIM  162
#define HID     256
#define KPAD1   192   // IN_DIM padded to multiple of 32
#define NB      ((N_NODES + 255) / 256)   // 196 scan blocks

typedef __bf16 bf16;
typedef __bf16 bf16x8 __attribute__((ext_vector_type(8)));
typedef __bf16 bf16x4 __attribute__((ext_vector_type(4)));
typedef float  f32x4  __attribute__((ext_vector_type(4)));
typedef float  f32x8  __attribute__((ext_vector_type(8)));
typedef float  f32x16 __attribute__((ext_vector_type(16)));

#define GLDS16(g, l) __builtin_amdgcn_global_load_lds( \
    (const __attribute__((address_space(1))) void*)(g), \
    (__attribute__((address_space(3))) void*)(l), 16, 0, 0)

// ---------------------------------------------------------------------------
// All 4 weight transposes in one launch. W[K][HID] f32 -> Wt[HID][KPAD] bf16.
__device__ __forceinline__ void wt_one(const float* W, bf16* Wt, int K, int KPAD, int idx)
{
    int n = idx / KPAD;
    int k = idx - n * KPAD;
    Wt[idx] = (k < K) ? (bf16)W[(size_t)k * HID + n] : (bf16)0.0f;
}

__global__ void wt_transpose_all(const float* __restrict__ m1aw, const float* __restrict__ m1bw,
                                 const float* __restrict__ m2aw, const float* __restrict__ m2bw,
                                 bf16* __restrict__ Wt1, bf16* __restrict__ Wt2,
                                 bf16* __restrict__ Wt3, bf16* __restrict__ Wt4)
{
    const int R1 = HID * KPAD1;
    const int R2 = HID * HID;
    int idx = blockIdx.x * blockDim.x + threadIdx.x;
    if (idx < R1)                 wt_one(m1aw, Wt1, IN_DIM, KPAD1, idx);
    else if (idx < R1 + R2)       wt_one(m1bw, Wt2, HID, HID, idx - R1);
    else if (idx < R1 + 2 * R2)   wt_one(m2aw, Wt3, HID, HID, idx - R1 - R2);
    else if (idx < R1 + 3 * R2)   wt_one(m2bw, Wt4, HID, HID, idx - R1 - 2 * R2);
}

// ---------------------------------------------------------------------------
// feat f32 [N, IN_DIM] -> featbf bf16 [N, KPAD1] (cols >= IN_DIM zeroed).
__global__ void feat_to_bf16(const float* __restrict__ feat, bf16* __restrict__ featbf)
{
    int idx = blockIdx.x * blockDim.x + threadIdx.x;  // over N*KPAD1/4
    int r = idx / (KPAD1 / 4);
    int c4 = (idx - r * (KPAD1 / 4)) * 4;
    if (r >= N_NODES) return;
    bf16x4 o;
#pragma unroll
    for (int j = 0; j < 4; ++j) {
        int c = c4 + j;
        o[j] = (c < IN_DIM) ? (bf16)feat[(size_t)r * IN_DIM + c] : (bf16)0.0f;
    }
    *(bf16x4*)(featbf + (size_t)r * KPAD1 + c4) = o;
}

// ---------------------------------------------------------------------------
// colsum8[b&7][c] += partial column sums of feat.
__global__ void colsum_feat8(const float* __restrict__ feat, float* __restrict__ colsum8)
{
    int c  = threadIdx.x;
    int r0 = blockIdx.x * 50;
    if (c >= IN_DIM) return;
    float acc = 0.0f;
#pragma unroll 2
    for (int i = 0; i < 50; ++i) {
        int r = r0 + i;
        if (r < N_NODES) acc += feat[(size_t)r * IN_DIM + c];
    }
    atomicAdd(&colsum8[(blockIdx.x & 7) * KPAD1 + c], acc);
}

// ---------------------------------------------------------------------------
// CSR build.
__global__ void degree_hist(const int* __restrict__ dst, int* __restrict__ deg)
{
    int e = blockIdx.x * blockDim.x + threadIdx.x;
    atomicAdd(&deg[dst[e]], 1);
}

__global__ void block_degsum(const int* __restrict__ deg, int* __restrict__ bsum)
{
    __shared__ int s[256];
    int t = threadIdx.x;
    int idx = blockIdx.x * 256 + t;
    int v = (idx < N_NODES) ? deg[idx] : 0;
    s[t] = v;
    __syncthreads();
    for (int off = 128; off > 0; off >>= 1) {
        if (t < off) s[t] += s[t + off];
        __syncthreads();
    }
    if (t == 0) bsum[blockIdx.x] = s[0];
}

__global__ void scan_bsum(const int* __restrict__ bsum, int* __restrict__ gsum)
{
    __shared__ int s[256];
    int t = threadIdx.x;
    int v = (t < NB) ? bsum[t] : 0;
    s[t] = v;
    __syncthreads();
    for (int off = 1; off < 256; off <<= 1) {
        int u = (t >= off) ? s[t - off] : 0;
        __syncthreads();
        s[t] += u;
        __syncthreads();
    }
    gsum[t] = s[t] - v;
}

__global__ void block_scan_write(const int* __restrict__ deg, const int* __restrict__ gsum,
                                 int* __restrict__ rowptr, int* __restrict__ cursor)
{
    __shared__ int s[256];
    int t = threadIdx.x;
    int idx = blockIdx.x * 256 + t;
    int v = (idx < N_NODES) ? deg[idx] : 0;
    s[t] = v;
    __syncthreads();
    for (int off = 1; off < 256; off <<= 1) {
        int u = (t >= off) ? s[t - off] : 0;
        __syncthreads();
        s[t] += u;
        __syncthreads();
    }
    int excl = s[t] - v + gsum[blockIdx.x];
    if (idx < N_NODES) {
        rowptr[idx] = excl;
        cursor[idx] = excl;
    }
    if (idx == 0) rowptr[N_NODES] = N_EDGES;
}

__global__ void csr_fill(const int* __restrict__ src, const int* __restrict__ dst,
                         int* __restrict__ cursor, int* __restrict__ csr_src)
{
    int e = blockIdx.x * blockDim.x + threadIdx.x;
    int p = atomicAdd(&cursor[dst[e]], 1);
    csr_src[p] = src[e];
}

// ---------------------------------------------------------------------------
// Column-sliced gather, layer 1.
// Grid = tiles*8; block b: group g = b&7 -> XCD g (round-robin dispatch).
// Group g owns cols [24g, 24g+24) = 48B per row; per-XCD slice = 2.4 MB (L2-fits).
// Wave = one (node, group). rb=lane>>2 indexes 16 src rows per round;
// c4=lane&3 covers three 16B chunks (c4<3). xor-shuffle reduce over rb.
__global__ void gather1cs(const bf16* __restrict__ featbf,
                          const int* __restrict__ rowptr,
                          const int* __restrict__ csr_src,
                          bf16* __restrict__ xsum)
{
    const int g    = blockIdx.x & 7;
    const int tile = blockIdx.x >> 3;
    const int wave = threadIdx.x >> 6;
    const int lane = threadIdx.x & 63;
    const int n = tile * 4 + wave;
    if (n >= N_NODES) return;
    const int rb = lane >> 2;          // row batch 0..15
    const int c4 = lane & 3;           // 16B chunk within slice
    const bool act = (c4 < 3);         // 3 x 16B = 48B slice
    const int ce = (3 * g + c4) * 8;   // element offset within row

    f32x8 acc;
#pragma unroll
    for (int j = 0; j < 8; ++j) acc[j] = 0.0f;
    if (rb == 0 && act) {
        bf16x8 t0 = *(const bf16x8*)(featbf + (size_t)n * KPAD1 + ce);
#pragma unroll
        for (int j = 0; j < 8; ++j) acc[j] = (float)t0[j];
    }

    const int r0 = rowptr[n];
    const int je = rowptr[n + 1];
    for (int jb = r0; jb < je; jb += 16) {
        int j = jb + rb;
        if (j < je) {
            int s = __builtin_nontemporal_load(csr_src + j);
            if (act) {
                bf16x8 u = *(const bf16x8*)(featbf + (size_t)s * KPAD1 + ce);
#pragma unroll
                for (int q = 0; q < 8; ++q) acc[q] += (float)u[q];
            }
        }
    }

#pragma unroll
    for (int q = 0; q < 8; ++q) {
        acc[q] += __shfl_xor(acc[q], 4, 64);
        acc[q] += __shfl_xor(acc[q], 8, 64);
        acc[q] += __shfl_xor(acc[q], 16, 64);
        acc[q] += __shfl_xor(acc[q], 32, 64);
    }

    if (rb == 0 && act) {
        bf16x8 o;
#pragma unroll
        for (int q = 0; q < 8; ++q) o[q] = (bf16)acc[q];
        __builtin_nontemporal_store(o, (bf16x8*)(xsum + (size_t)n * KPAD1 + ce));
    }
}

// ---------------------------------------------------------------------------
// Column-sliced gather, layer 2. Group g owns cols [32g, 32g+32) = 64B;
// per-XCD slice = 3.2 MB. All 4 chunk lanes active.
__global__ void gather2cs(const bf16* __restrict__ node1,
                          const int* __restrict__ rowptr,
                          const int* __restrict__ csr_src,
                          bf16* __restrict__ y2)
{
    const int g    = blockIdx.x & 7;
    const int tile = blockIdx.x >> 3;
    const int wave = threadIdx.x >> 6;
    const int lane = threadIdx.x & 63;
    const int n = tile * 4 + wave;
    if (n >= N_NODES) return;
    const int rb = lane >> 2;          // row batch 0..15
    const int c4 = lane & 3;           // 16B chunk within 64B slice
    const int ce = (4 * g + c4) * 8;   // element offset within row

    f32x8 acc;
#pragma unroll
    for (int j = 0; j < 8; ++j) acc[j] = 0.0f;
    if (rb == 0) {
        bf16x8 t0 = *(const bf16x8*)(node1 + (size_t)n * HID + ce);
#pragma unroll
        for (int j = 0; j < 8; ++j) acc[j] = (float)t0[j];
    }

    const int r0 = rowptr[n];
    const int je = rowptr[n + 1];
    for (int jb = r0; jb < je; jb += 16) {
        int j = jb + rb;
        if (j < je) {
            int s = __builtin_nontemporal_load(csr_src + j);
            bf16x8 u = *(const bf16x8*)(node1 + (size_t)s * HID + ce);
#pragma unroll
            for (int q = 0; q < 8; ++q) acc[q] += (float)u[q];
        }
    }

#pragma unroll
    for (int q = 0; q < 8; ++q) {
        acc[q] += __shfl_xor(acc[q], 4, 64);
        acc[q] += __shfl_xor(acc[q], 8, 64);
        acc[q] += __shfl_xor(acc[q], 16, 64);
        acc[q] += __shfl_xor(acc[q], 32, 64);
    }

    if (rb == 0) {
        bf16x8 o;
#pragma unroll
        for (int q = 0; q < 8; ++q) o[q] = (bf16)acc[q];
        __builtin_nontemporal_store(o, (bf16x8*)(y2 + (size_t)n * HID + ce));
    }
}

// ---------------------------------------------------------------------------
// GEMM v2 (+ optional fused column-sum of the post-relu output).
template<int KPAD>
__launch_bounds__(256)
__global__ void gemm_relu2(const bf16* __restrict__ X,
                           const bf16* __restrict__ Wt,
                           const float* __restrict__ bias,
                           bf16* __restrict__ out_bf,
                           float* __restrict__ colsum,   // nullable
                           int M)
{
    __shared__ __align__(128) bf16 sB[8192];   // 16 KB
    __shared__ float cs[256];

    const int tid  = threadIdx.x;
    const int w    = tid >> 6;
    const int lane = tid & 63;
    const int p    = lane >> 5;
    const int cn   = lane & 31;
    const int m_base = blockIdx.x * 128 + w * 32;

    int arow = m_base + cn;
    if (arow >= M) arow = M - 1;   // clamp (stores guarded)

    f32x16 acc[8];
#pragma unroll
    for (int j = 0; j < 8; ++j)
#pragma unroll
        for (int r = 0; r < 16; ++r) acc[j][r] = 0.0f;

    for (int k0 = 0; k0 < KPAD; k0 += 32) {
        __syncthreads();
#pragma unroll
        for (int i = 0; i < 4; ++i) {
            int fb = w * 4 + i;
            int j  = fb >> 1;
            int kk = fb & 1;
            const bf16* g = Wt + (size_t)(j * 32 + cn) * KPAD + k0 + kk * 16 + p * 8;
            GLDS16(g, sB + fb * 512);
        }
        __syncthreads();

#pragma unroll
        for (int kk = 0; kk < 2; ++kk) {
            bf16x8 a = *(const bf16x8*)(X + (size_t)arow * KPAD + k0 + kk * 16 + p * 8);
#pragma unroll
            for (int j = 0; j < 8; ++j) {
                bf16x8 b = *(const bf16x8*)(sB + (j * 2 + kk) * 512 + lane * 8);
                acc[j] = __builtin_amdgcn_mfma_f32_32x32x16_bf16(a, b, acc[j], 0, 0, 0);
            }
        }
    }

    if (colsum) {
        cs[tid] = 0.0f;
        __syncthreads();
    }

#pragma unroll
    for (int j = 0; j < 8; ++j) {
        const int col = j * 32 + cn;
        const float bv = bias[col];
        float part = 0.0f;
#pragma unroll
        for (int r = 0; r < 16; ++r) {
            int rl = (r & 3) + 8 * (r >> 2) + 4 * p;
            int mo = m_base + rl;
            if (mo < M) {
                float v = acc[j][r] + bv;
                v = v > 0.0f ? v : 0.0f;
                out_bf[(size_t)mo * HID + col] = (bf16)v;
                part += v;
            }
        }
        if (colsum) {
            part += __shfl_xor(part, 32, 64);   // combine the two p-halves
            if (p == 0) atomicAdd(&cs[col], part);
        }
    }

    if (colsum) {
        __syncthreads();
        atomicAdd(&colsum[tid], cs[tid]);
    }
}

// ---------------------------------------------------------------------------
// Graph head: three GEMVs + sum + final GEMV, single block of 256 threads.
__global__ void graph_head(const float* __restrict__ cs0_8,
                           const float* __restrict__ cs1,
                           const float* __restrict__ cs2,
                           const float* __restrict__ g0w, const float* __restrict__ g0b,
                           const float* __restrict__ g1w, const float* __restrict__ g1b,
                           const float* __restrict__ g2w, const float* __restrict__ g2b,
                           const float* __restrict__ glw, const float* __restrict__ glb,
                           float* __restrict__ gvec)
{
    __shared__ float v0[IN_DIM], v1[HID], v2[HID], gs[HID];
    int t = threadIdx.x;
    if (t < IN_DIM) {
        float s = 0.0f;
#pragma unroll
        for (int i = 0; i < 8; ++i) s += cs0_8[i * KPAD1 + t];
        v0[t] = s;
    }
    v1[t] = cs1[t];
    v2[t] = cs2[t];
    __syncthreads();

    float a0 = 0.0f, a1 = 0.0f, a2 = 0.0f;
    for (int k = 0; k < IN_DIM; ++k) a0 += v0[k] * g0w[k * HID + t];
    for (int k = 0; k < HID; ++k) {
        a1 += v1[k] * g1w[k * HID + t];
        a2 += v2[k] * g2w[k * HID + t];
    }
    float e0 = fmaxf(a0 + g0b[t], 0.0f);
    float e1 = fmaxf(a1 + g1b[t], 0.0f);
    float e2 = fmaxf(a2 + g2b[t], 0.0f);
    gs[t] = e0 + e1 + e2;
    __syncthreads();

    float a3 = 0.0f;
    for (int k = 0; k < HID; ++k) a3 += gs[k] * glw[k * HID + t];
    gvec[t] = fmaxf(a3 + glb[t], 0.0f);
}

// ---------------------------------------------------------------------------
// out[n,c] = node2[n,c](bf16) + gvec[c] (f32 out); 4 elements per thread.
__global__ void final_add(const bf16* __restrict__ node2,
                          const float* __restrict__ gvec,
                          float* __restrict__ out)
{
    int idx = blockIdx.x * blockDim.x + threadIdx.x;
    size_t base = (size_t)idx * 4;
    int c = (int)(base & (HID - 1));
    bf16x4 v = *(const bf16x4*)(node2 + base);
    f32x4 g = *(const f32x4*)(gvec + c);
    f32x4 o;
#pragma unroll
    for (int j = 0; j < 4; ++j) o[j] = (float)v[j] + g[j];
    *(f32x4*)(out + base) = o;
}

// ---------------------------------------------------------------------------
extern "C" void kernel_launch(void* const* d_in, const int* in_sizes, int n_in,
                              void* d_out, int out_size, void* d_ws, size_t ws_size,
                              hipStream_t stream)
{
    const float* feat = (const float*)d_in[0];
    const int*   ei   = (const int*)d_in[1];
    const int*   src  = ei;
    const int*   dst  = ei + N_EDGES;
    const float* g0w = (const float*)d_in[2],  *g0b = (const float*)d_in[3];
    const float* g1w = (const float*)d_in[4],  *g1b = (const float*)d_in[5];
    const float* g2w = (const float*)d_in[6],  *g2b = (const float*)d_in[7];
    const float* glw = (const float*)d_in[8],  *glb = (const float*)d_in[9];
    const float* m1aw = (const float*)d_in[10], *m1ab = (const float*)d_in[11];
    const float* m1bw = (const float*)d_in[12], *m1bb = (const float*)d_in[13];
    const float* m2aw = (const float*)d_in[14], *m2ab = (const float*)d_in[15];
    const float* m2bw = (const float*)d_in[16], *m2bb = (const float*)d_in[17];
    float* out = (float*)d_out;

    char* ws = (char*)d_ws;
    size_t off = 0;
    auto alloc = [&](size_t bytes) -> void* {
        void* p = ws + off;
        off += (bytes + 255) & ~(size_t)255;
        return p;
    };
    bf16*  featbf = (bf16*)alloc((size_t)N_NODES * KPAD1 * 2);
    bf16*  xsum  = (bf16*) alloc((size_t)N_NODES * KPAD1 * 2);
    bf16*  y2    = (bf16*) alloc((size_t)N_NODES * HID * 2);
    bf16*  node2 = (bf16*) alloc((size_t)N_NODES * HID * 2);
    bf16*  h1    = (bf16*) alloc((size_t)N_NODES * HID * 2);   // reused as h2
    bf16*  node1 = (bf16*) alloc((size_t)N_NODES * HID * 2);
    bf16*  Wt1   = (bf16*) alloc((size_t)HID * KPAD1 * 2);
    bf16*  Wt2   = (bf16*) alloc((size_t)HID * HID * 2);
    bf16*  Wt3   = (bf16*) alloc((size_t)HID * HID * 2);
    bf16*  Wt4   = (bf16*) alloc((size_t)HID * HID * 2);
    int*   deg     = (int*)alloc((size_t)N_NODES * 4);
    int*   rowptr  = (int*)alloc((size_t)(N_NODES + 1) * 4);
    int*   cursor  = (int*)alloc((size_t)N_NODES * 4);
    int*   csr_src = (int*)alloc((size_t)N_EDGES * 4);
    int*   bsum    = (int*)alloc(256 * 4);
    int*   gsum    = (int*)alloc(256 * 4);
    float* csums   = (float*)alloc((8 * KPAD1 + 256 + 256 + 256) * 4);
    float* colsum0_8 = csums;                    // 8 x 192 partial slots
    float* colsum1   = csums + 8 * KPAD1;        // 256
    float* colsum2   = csums + 8 * KPAD1 + 256;  // 256
    float* gvec      = csums + 8 * KPAD1 + 512;  // 256

    hipMemsetAsync(csums, 0, (8 * KPAD1 + 512) * 4, stream);
    hipMemsetAsync(deg, 0, (size_t)N_NODES * 4, stream);

    // all 4 weight transposes, one launch
    wt_transpose_all<<<(HID * KPAD1 + 3 * HID * HID + 255) / 256, 256, 0, stream>>>(
        m1aw, m1bw, m2aw, m2bw, Wt1, Wt2, Wt3, Wt4);

    // feat -> bf16 (wide vectorized grid)
    feat_to_bf16<<<((size_t)N_NODES * (KPAD1 / 4) + 255) / 256, 256, 0, stream>>>(feat, featbf);
    // colsum0 partials (8-slot spread)
    colsum_feat8<<<1000, 192, 0, stream>>>(feat, colsum0_8);

    // CSR build (grouped by dst)
    degree_hist<<<N_EDGES / 256, 256, 0, stream>>>(dst, deg);
    block_degsum<<<NB, 256, 0, stream>>>(deg, bsum);
    scan_bsum<<<1, 256, 0, stream>>>(bsum, gsum);
    block_scan_write<<<NB, 256, 0, stream>>>(deg, gsum, rowptr, cursor);
    csr_fill<<<N_EDGES / 256, 256, 0, stream>>>(src, dst, cursor, csr_src);

    const int tiles = (N_NODES + 3) / 4;
    // xsum = bf16(feat + gather(feat)) — column-sliced, XCD-pinned
    gather1cs<<<tiles * 8, 256, 0, stream>>>(featbf, rowptr, csr_src, xsum);

    const int gblocks = (N_NODES + 127) / 128;
    // h1 = relu(xsum @ m1a_w + b)
    gemm_relu2<KPAD1><<<gblocks, 256, 0, stream>>>(xsum, Wt1, m1ab, h1, nullptr, N_NODES);
    // node1 = relu(h1 @ m1b_w + b), colsum1 fused
    gemm_relu2<HID><<<gblocks, 256, 0, stream>>>(h1, Wt2, m1bb, node1, colsum1, N_NODES);
    // y2 = bf16(node1 + gather(node1)) — column-sliced, XCD-pinned
    gather2cs<<<tiles * 8, 256, 0, stream>>>(node1, rowptr, csr_src, y2);
    // h2 = relu(y2 @ m2a_w + b)  (reuse h1 buffer)
    gemm_relu2<HID><<<gblocks, 256, 0, stream>>>(y2, Wt3, m2ab, h1, nullptr, N_NODES);
    // node2 = relu(h2 @ m2b_w + b), colsum2 fused
    gemm_relu2<HID><<<gblocks, 256, 0, stream>>>(h1, Wt4, m2bb, node2, colsum2, N_NODES);
    // graph head -> gvec = g_last
    graph_head<<<1, 256, 0, stream>>>(colsum0_8, colsum1, colsum2,
                                      g0w, g0b, g1w, g1b, g2w, g2b, glw, glb, gvec);
    // out = node2 + gvec
    final_add<<<((size_t)N_NODES * HID / 4 + 255) / 256, 256, 0, stream>>>(node2, gvec, out);
    (void)in_sizes; (void)n_in; (void)out_size; (void)ws_size;
}

// Round 3
// 659.817 us; speedup vs baseline: 1.1793x; 1.1793x over previous
//
#include <hip/hip_runtime.h>

#define N_NODES 50000
#define N_EDGES 800000
#define IN_DIM  162
#define HID     256
#define KPAD1   192   // IN_DIM padded to multiple of 32
#define NB      ((N_NODES + 255) / 256)   // 196 scan blocks

typedef __bf16 bf16;
typedef __bf16 bf16x8 __attribute__((ext_vector_type(8)));
typedef __bf16 bf16x4 __attribute__((ext_vector_type(4)));
typedef float  f32x4  __attribute__((ext_vector_type(4)));
typedef float  f32x8  __attribute__((ext_vector_type(8)));
typedef float  f32x16 __attribute__((ext_vector_type(16)));

#define GLDS16(g, l) __builtin_amdgcn_global_load_lds( \
    (const __attribute__((address_space(1))) void*)(g), \
    (__attribute__((address_space(3))) void*)(l), 16, 0, 0)

// ---------------------------------------------------------------------------
// All 4 weight transposes in one launch. W[K][HID] f32 -> Wt[HID][KPAD] bf16.
__device__ __forceinline__ void wt_one(const float* W, bf16* Wt, int K, int KPAD, int idx)
{
    int n = idx / KPAD;
    int k = idx - n * KPAD;
    Wt[idx] = (k < K) ? (bf16)W[(size_t)k * HID + n] : (bf16)0.0f;
}

__global__ void wt_transpose_all(const float* __restrict__ m1aw, const float* __restrict__ m1bw,
                                 const float* __restrict__ m2aw, const float* __restrict__ m2bw,
                                 bf16* __restrict__ Wt1, bf16* __restrict__ Wt2,
                                 bf16* __restrict__ Wt3, bf16* __restrict__ Wt4)
{
    const int R1 = HID * KPAD1;
    const int R2 = HID * HID;
    int idx = blockIdx.x * blockDim.x + threadIdx.x;
    if (idx < R1)                 wt_one(m1aw, Wt1, IN_DIM, KPAD1, idx);
    else if (idx < R1 + R2)       wt_one(m1bw, Wt2, HID, HID, idx - R1);
    else if (idx < R1 + 2 * R2)   wt_one(m2aw, Wt3, HID, HID, idx - R1 - R2);
    else if (idx < R1 + 3 * R2)   wt_one(m2bw, Wt4, HID, HID, idx - R1 - 2 * R2);
}

// ---------------------------------------------------------------------------
// feat f32 [N, IN_DIM] -> featbf bf16 TILED [8][N][24] (cols >= IN_DIM zeroed).
// Group g owns cols [24g, 24g+24) stored contiguously (2.4 MB per group).
__global__ void feat_to_bf16(const float* __restrict__ feat, bf16* __restrict__ featbf)
{
    int idx = blockIdx.x * blockDim.x + threadIdx.x;  // over N*KPAD1/4
    int r = idx / (KPAD1 / 4);
    int c4 = (idx - r * (KPAD1 / 4)) * 4;
    if (r >= N_NODES) return;
    bf16x4 o;
#pragma unroll
    for (int j = 0; j < 4; ++j) {
        int c = c4 + j;
        o[j] = (c < IN_DIM) ? (bf16)feat[(size_t)r * IN_DIM + c] : (bf16)0.0f;
    }
    int gch = c4 / 24;
    int off = c4 - gch * 24;
    *(bf16x4*)(featbf + ((size_t)gch * N_NODES + r) * 24 + off) = o;
}

// ---------------------------------------------------------------------------
// colsum8[b&7][c] += partial column sums of feat (reads original f32 feat).
__global__ void colsum_feat8(const float* __restrict__ feat, float* __restrict__ colsum8)
{
    int c  = threadIdx.x;
    int r0 = blockIdx.x * 50;
    if (c >= IN_DIM) return;
    float acc = 0.0f;
#pragma unroll 2
    for (int i = 0; i < 50; ++i) {
        int r = r0 + i;
        if (r < N_NODES) acc += feat[(size_t)r * IN_DIM + c];
    }
    atomicAdd(&colsum8[(blockIdx.x & 7) * KPAD1 + c], acc);
}

// ---------------------------------------------------------------------------
// CSR build.
__global__ void degree_hist(const int* __restrict__ dst, int* __restrict__ deg)
{
    int e = blockIdx.x * blockDim.x + threadIdx.x;
    atomicAdd(&deg[dst[e]], 1);
}

__global__ void block_degsum(const int* __restrict__ deg, int* __restrict__ bsum)
{
    __shared__ int s[256];
    int t = threadIdx.x;
    int idx = blockIdx.x * 256 + t;
    int v = (idx < N_NODES) ? deg[idx] : 0;
    s[t] = v;
    __syncthreads();
    for (int off = 128; off > 0; off >>= 1) {
        if (t < off) s[t] += s[t + off];
        __syncthreads();
    }
    if (t == 0) bsum[blockIdx.x] = s[0];
}

__global__ void scan_bsum(const int* __restrict__ bsum, int* __restrict__ gsum)
{
    __shared__ int s[256];
    int t = threadIdx.x;
    int v = (t < NB) ? bsum[t] : 0;
    s[t] = v;
    __syncthreads();
    for (int off = 1; off < 256; off <<= 1) {
        int u = (t >= off) ? s[t - off] : 0;
        __syncthreads();
        s[t] += u;
        __syncthreads();
    }
    gsum[t] = s[t] - v;
}

__global__ void block_scan_write(const int* __restrict__ deg, const int* __restrict__ gsum,
                                 int* __restrict__ rowptr, int* __restrict__ cursor)
{
    __shared__ int s[256];
    int t = threadIdx.x;
    int idx = blockIdx.x * 256 + t;
    int v = (idx < N_NODES) ? deg[idx] : 0;
    s[t] = v;
    __syncthreads();
    for (int off = 1; off < 256; off <<= 1) {
        int u = (t >= off) ? s[t - off] : 0;
        __syncthreads();
        s[t] += u;
        __syncthreads();
    }
    int excl = s[t] - v + gsum[blockIdx.x];
    if (idx < N_NODES) {
        rowptr[idx] = excl;
        cursor[idx] = excl;
    }
    if (idx == 0) rowptr[N_NODES] = N_EDGES;
}

__global__ void csr_fill(const int* __restrict__ src, const int* __restrict__ dst,
                         int* __restrict__ cursor, int* __restrict__ csr_src)
{
    int e = blockIdx.x * blockDim.x + threadIdx.x;
    int p = atomicAdd(&cursor[dst[e]], 1);
    csr_src[p] = src[e];
}

// ---------------------------------------------------------------------------
// Tiled gather, layer 1. featbf/xsum are [8][N][24] bf16.
// Block b: group g = b&7 -> XCD g (round-robin). Group slice = 2.4 MB, L2-fits.
// Wave = 16 nodes; lane-quad (c4<3 active, 48B) walks its node's edges serially.
__global__ void gather1t(const bf16* __restrict__ featbf,
                         const int* __restrict__ rowptr,
                         const int* __restrict__ csr_src,
                         bf16* __restrict__ xsum)
{
    const int g    = blockIdx.x & 7;
    const int tile = blockIdx.x >> 3;
    const int wv   = threadIdx.x >> 6;
    const int lane = threadIdx.x & 63;
    const int q    = lane >> 2;          // node within wave 0..15
    const int c4   = lane & 3;           // 16B chunk; c4<3 active (48B)
    const int n    = tile * 64 + wv * 16 + q;
    const bool valid = (n < N_NODES);
    const bool act   = valid && (c4 < 3);
    const int  ce    = c4 * 8;
    const bf16* base = featbf + (size_t)g * N_NODES * 24;

    f32x8 acc;
#pragma unroll
    for (int j = 0; j < 8; ++j) acc[j] = 0.0f;
    if (act) {
        bf16x8 t0 = *(const bf16x8*)(base + (size_t)n * 24 + ce);
#pragma unroll
        for (int j = 0; j < 8; ++j) acc[j] = (float)t0[j];
    }

    int jj = valid ? rowptr[n] : 0;
    int je = valid ? rowptr[n + 1] : 0;
    while (__ballot(jj < je)) {
        if (jj < je) {
            int s = __builtin_nontemporal_load(csr_src + jj);
            if (c4 < 3) {
                bf16x8 u = *(const bf16x8*)(base + (size_t)s * 24 + ce);
#pragma unroll
                for (int t = 0; t < 8; ++t) acc[t] += (float)u[t];
            }
            ++jj;
        }
    }

    if (act) {
        bf16x8 o;
#pragma unroll
        for (int t = 0; t < 8; ++t) o[t] = (bf16)acc[t];
        __builtin_nontemporal_store(o,
            (bf16x8*)(xsum + ((size_t)g * N_NODES + n) * 24 + ce));
    }
}

// ---------------------------------------------------------------------------
// Tiled gather, layer 2. node1/y2 are [8][N][32] bf16 (3.2 MB per group).
__global__ void gather2t(const bf16* __restrict__ node1,
                         const int* __restrict__ rowptr,
                         const int* __restrict__ csr_src,
                         bf16* __restrict__ y2)
{
    const int g    = blockIdx.x & 7;
    const int tile = blockIdx.x >> 3;
    const int wv   = threadIdx.x >> 6;
    const int lane = threadIdx.x & 63;
    const int q    = lane >> 2;
    const int c4   = lane & 3;
    const int n    = tile * 64 + wv * 16 + q;
    const bool valid = (n < N_NODES);
    const int  ce    = c4 * 8;
    const bf16* base = node1 + (size_t)g * N_NODES * 32;

    f32x8 acc;
#pragma unroll
    for (int j = 0; j < 8; ++j) acc[j] = 0.0f;
    if (valid) {
        bf16x8 t0 = *(const bf16x8*)(base + (size_t)n * 32 + ce);
#pragma unroll
        for (int j = 0; j < 8; ++j) acc[j] = (float)t0[j];
    }

    int jj = valid ? rowptr[n] : 0;
    int je = valid ? rowptr[n + 1] : 0;
    while (__ballot(jj < je)) {
        if (jj < je) {
            int s = __builtin_nontemporal_load(csr_src + jj);
            bf16x8 u = *(const bf16x8*)(base + (size_t)s * 32 + ce);
#pragma unroll
            for (int t = 0; t < 8; ++t) acc[t] += (float)u[t];
            ++jj;
        }
    }

    if (valid) {
        bf16x8 o;
#pragma unroll
        for (int t = 0; t < 8; ++t) o[t] = (bf16)acc[t];
        __builtin_nontemporal_store(o,
            (bf16x8*)(y2 + ((size_t)g * N_NODES + n) * 32 + ce));
    }
}

// ---------------------------------------------------------------------------
// GEMM v2 (+ optional fused column-sum of the post-relu output).
// ACHUNK: 0 = X linear [M][KPAD]; else X tiled [KPAD/ACHUNK][N_NODES][ACHUNK].
// OCHUNK: 0 = out linear [M][HID]; else out tiled [HID/32][N_NODES][32].
template<int KPAD, int ACHUNK, int OCHUNK>
__launch_bounds__(256)
__global__ void gemm_relu2(const bf16* __restrict__ X,
                           const bf16* __restrict__ Wt,
                           const float* __restrict__ bias,
                           bf16* __restrict__ out_bf,
                           float* __restrict__ colsum,   // nullable
                           int M)
{
    __shared__ __align__(128) bf16 sB[8192];   // 16 KB
    __shared__ float cs[256];

    const int tid  = threadIdx.x;
    const int w    = tid >> 6;
    const int lane = tid & 63;
    const int p    = lane >> 5;
    const int cn   = lane & 31;
    const int m_base = blockIdx.x * 128 + w * 32;

    int arow = m_base + cn;
    if (arow >= M) arow = M - 1;   // clamp (stores guarded)

    f32x16 acc[8];
#pragma unroll
    for (int j = 0; j < 8; ++j)
#pragma unroll
        for (int r = 0; r < 16; ++r) acc[j][r] = 0.0f;

    for (int k0 = 0; k0 < KPAD; k0 += 32) {
        __syncthreads();
#pragma unroll
        for (int i = 0; i < 4; ++i) {
            int fb = w * 4 + i;
            int j  = fb >> 1;
            int kk = fb & 1;
            const bf16* g = Wt + (size_t)(j * 32 + cn) * KPAD + k0 + kk * 16 + p * 8;
            GLDS16(g, sB + fb * 512);
        }
        __syncthreads();

#pragma unroll
        for (int kk = 0; kk < 2; ++kk) {
            bf16x8 a;
            if constexpr (ACHUNK == 0) {
                a = *(const bf16x8*)(X + (size_t)arow * KPAD + k0 + kk * 16 + p * 8);
            } else {
                const int e   = k0 + kk * 16 + p * 8;
                const int gch = e / ACHUNK;
                const int off = e - gch * ACHUNK;
                a = *(const bf16x8*)(X + ((size_t)gch * N_NODES + arow) * ACHUNK + off);
            }
#pragma unroll
            for (int j = 0; j < 8; ++j) {
                bf16x8 b = *(const bf16x8*)(sB + (j * 2 + kk) * 512 + lane * 8);
                acc[j] = __builtin_amdgcn_mfma_f32_32x32x16_bf16(a, b, acc[j], 0, 0, 0);
            }
        }
    }

    if (colsum) {
        cs[tid] = 0.0f;
        __syncthreads();
    }

#pragma unroll
    for (int j = 0; j < 8; ++j) {
        const int col = j * 32 + cn;
        const float bv = bias[col];
        float part = 0.0f;
#pragma unroll
        for (int r = 0; r < 16; ++r) {
            int rl = (r & 3) + 8 * (r >> 2) + 4 * p;
            int mo = m_base + rl;
            if (mo < M) {
                float v = acc[j][r] + bv;
                v = v > 0.0f ? v : 0.0f;
                if constexpr (OCHUNK == 0)
                    out_bf[(size_t)mo * HID + col] = (bf16)v;
                else
                    out_bf[((size_t)j * N_NODES + mo) * OCHUNK + cn] = (bf16)v;
                part += v;
            }
        }
        if (colsum) {
            part += __shfl_xor(part, 32, 64);   // combine the two p-halves
            if (p == 0) atomicAdd(&cs[col], part);
        }
    }

    if (colsum) {
        __syncthreads();
        atomicAdd(&colsum[tid], cs[tid]);
    }
}

// ---------------------------------------------------------------------------
// Graph head: three GEMVs + sum + final GEMV, single block of 256 threads.
__global__ void graph_head(const float* __restrict__ cs0_8,
                           const float* __restrict__ cs1,
                           const float* __restrict__ cs2,
                           const float* __restrict__ g0w, const float* __restrict__ g0b,
                           const float* __restrict__ g1w, const float* __restrict__ g1b,
                           const float* __restrict__ g2w, const float* __restrict__ g2b,
                           const float* __restrict__ glw, const float* __restrict__ glb,
                           float* __restrict__ gvec)
{
    __shared__ float v0[IN_DIM], v1[HID], v2[HID], gs[HID];
    int t = threadIdx.x;
    if (t < IN_DIM) {
        float s = 0.0f;
#pragma unroll
        for (int i = 0; i < 8; ++i) s += cs0_8[i * KPAD1 + t];
        v0[t] = s;
    }
    v1[t] = cs1[t];
    v2[t] = cs2[t];
    __syncthreads();

    float a0 = 0.0f, a1 = 0.0f, a2 = 0.0f;
    for (int k = 0; k < IN_DIM; ++k) a0 += v0[k] * g0w[k * HID + t];
    for (int k = 0; k < HID; ++k) {
        a1 += v1[k] * g1w[k * HID + t];
        a2 += v2[k] * g2w[k * HID + t];
    }
    float e0 = fmaxf(a0 + g0b[t], 0.0f);
    float e1 = fmaxf(a1 + g1b[t], 0.0f);
    float e2 = fmaxf(a2 + g2b[t], 0.0f);
    gs[t] = e0 + e1 + e2;
    __syncthreads();

    float a3 = 0.0f;
    for (int k = 0; k < HID; ++k) a3 += gs[k] * glw[k * HID + t];
    gvec[t] = fmaxf(a3 + glb[t], 0.0f);
}

// ---------------------------------------------------------------------------
// out[n,c] = node2[n,c](bf16) + gvec[c] (f32 out); 4 elements per thread.
__global__ void final_add(const bf16* __restrict__ node2,
                          const float* __restrict__ gvec,
                          float* __restrict__ out)
{
    int idx = blockIdx.x * blockDim.x + threadIdx.x;
    size_t base = (size_t)idx * 4;
    int c = (int)(base & (HID - 1));
    bf16x4 v = *(const bf16x4*)(node2 + base);
    f32x4 g = *(const f32x4*)(gvec + c);
    f32x4 o;
#pragma unroll
    for (int j = 0; j < 4; ++j) o[j] = (float)v[j] + g[j];
    *(f32x4*)(out + base) = o;
}

// ---------------------------------------------------------------------------
extern "C" void kernel_launch(void* const* d_in, const int* in_sizes, int n_in,
                              void* d_out, int out_size, void* d_ws, size_t ws_size,
                              hipStream_t stream)
{
    const float* feat = (const float*)d_in[0];
    const int*   ei   = (const int*)d_in[1];
    const int*   src  = ei;
    const int*   dst  = ei + N_EDGES;
    const float* g0w = (const float*)d_in[2],  *g0b = (const float*)d_in[3];
    const float* g1w = (const float*)d_in[4],  *g1b = (const float*)d_in[5];
    const float* g2w = (const float*)d_in[6],  *g2b = (const float*)d_in[7];
    const float* glw = (const float*)d_in[8],  *glb = (const float*)d_in[9];
    const float* m1aw = (const float*)d_in[10], *m1ab = (const float*)d_in[11];
    const float* m1bw = (const float*)d_in[12], *m1bb = (const float*)d_in[13];
    const float* m2aw = (const float*)d_in[14], *m2ab = (const float*)d_in[15];
    const float* m2bw = (const float*)d_in[16], *m2bb = (const float*)d_in[17];
    float* out = (float*)d_out;

    char* ws = (char*)d_ws;
    size_t off = 0;
    auto alloc = [&](size_t bytes) -> void* {
        void* p = ws + off;
        off += (bytes + 255) & ~(size_t)255;
        return p;
    };
    bf16*  featbf = (bf16*)alloc((size_t)N_NODES * KPAD1 * 2);   // tiled [8][N][24]
    bf16*  xsum  = (bf16*) alloc((size_t)N_NODES * KPAD1 * 2);   // tiled [8][N][24]
    bf16*  y2    = (bf16*) alloc((size_t)N_NODES * HID * 2);     // tiled [8][N][32]
    bf16*  node2 = (bf16*) alloc((size_t)N_NODES * HID * 2);     // linear
    bf16*  h1    = (bf16*) alloc((size_t)N_NODES * HID * 2);     // linear (reused as h2)
    bf16*  node1 = (bf16*) alloc((size_t)N_NODES * HID * 2);     // tiled [8][N][32]
    bf16*  Wt1   = (bf16*) alloc((size_t)HID * KPAD1 * 2);
    bf16*  Wt2   = (bf16*) alloc((size_t)HID * HID * 2);
    bf16*  Wt3   = (bf16*) alloc((size_t)HID * HID * 2);
    bf16*  Wt4   = (bf16*) alloc((size_t)HID * HID * 2);
    int*   deg     = (int*)alloc((size_t)N_NODES * 4);
    int*   rowptr  = (int*)alloc((size_t)(N_NODES + 1) * 4);
    int*   cursor  = (int*)alloc((size_t)N_NODES * 4);
    int*   csr_src = (int*)alloc((size_t)N_EDGES * 4);
    int*   bsum    = (int*)alloc(256 * 4);
    int*   gsum    = (int*)alloc(256 * 4);
    float* csums   = (float*)alloc((8 * KPAD1 + 256 + 256 + 256) * 4);
    float* colsum0_8 = csums;                    // 8 x 192 partial slots
    float* colsum1   = csums + 8 * KPAD1;        // 256
    float* colsum2   = csums + 8 * KPAD1 + 256;  // 256
    float* gvec      = csums + 8 * KPAD1 + 512;  // 256

    hipMemsetAsync(csums, 0, (8 * KPAD1 + 512) * 4, stream);
    hipMemsetAsync(deg, 0, (size_t)N_NODES * 4, stream);

    // all 4 weight transposes, one launch
    wt_transpose_all<<<(HID * KPAD1 + 3 * HID * HID + 255) / 256, 256, 0, stream>>>(
        m1aw, m1bw, m2aw, m2bw, Wt1, Wt2, Wt3, Wt4);

    // feat -> bf16 tiled
    feat_to_bf16<<<((size_t)N_NODES * (KPAD1 / 4) + 255) / 256, 256, 0, stream>>>(feat, featbf);
    // colsum0 partials (8-slot spread)
    colsum_feat8<<<1000, 192, 0, stream>>>(feat, colsum0_8);

    // CSR build (grouped by dst)
    degree_hist<<<N_EDGES / 256, 256, 0, stream>>>(dst, deg);
    block_degsum<<<NB, 256, 0, stream>>>(deg, bsum);
    scan_bsum<<<1, 256, 0, stream>>>(bsum, gsum);
    block_scan_write<<<NB, 256, 0, stream>>>(deg, gsum, rowptr, cursor);
    csr_fill<<<N_EDGES / 256, 256, 0, stream>>>(src, dst, cursor, csr_src);

    const int gtiles = (N_NODES + 63) / 64;   // 16 nodes/wave x 4 waves
    // xsum = bf16(feat + gather(feat)) — tiled, XCD-pinned
    gather1t<<<gtiles * 8, 256, 0, stream>>>(featbf, rowptr, csr_src, xsum);

    const int gblocks = (N_NODES + 127) / 128;
    // h1 = relu(xsum @ m1a_w + b)          (A tiled24 -> linear out)
    gemm_relu2<KPAD1, 24, 0><<<gblocks, 256, 0, stream>>>(xsum, Wt1, m1ab, h1, nullptr, N_NODES);
    // node1 = relu(h1 @ m1b_w + b), colsum1 fused   (linear A -> tiled32 out)
    gemm_relu2<HID, 0, 32><<<gblocks, 256, 0, stream>>>(h1, Wt2, m1bb, node1, colsum1, N_NODES);
    // y2 = bf16(node1 + gather(node1)) — tiled, XCD-pinned
    gather2t<<<gtiles * 8, 256, 0, stream>>>(node1, rowptr, csr_src, y2);
    // h2 = relu(y2 @ m2a_w + b)  (reuse h1 buffer)  (A tiled32 -> linear out)
    gemm_relu2<HID, 32, 0><<<gblocks, 256, 0, stream>>>(y2, Wt3, m2ab, h1, nullptr, N_NODES);
    // node2 = relu(h2 @ m2b_w + b), colsum2 fused   (linear A -> linear out)
    gemm_relu2<HID, 0, 0><<<gblocks, 256, 0, stream>>>(h1, Wt4, m2bb, node2, colsum2, N_NODES);
    // graph head -> gvec = g_last
    graph_head<<<1, 256, 0, stream>>>(colsum0_8, colsum1, colsum2,
                                      g0w, g0b, g1w, g1b, g2w, g2b, glw, glb, gvec);
    // out = node2 + gvec
    final_add<<<((size_t)N_NODES * HID / 4 + 255) / 256, 256, 0, stream>>>(node2, gvec, out);
    (void)in_sizes; (void)n_in; (void)out_size; (void)ws_size;
}

// Round 4
// 607.684 us; speedup vs baseline: 1.2805x; 1.0858x over previous
//
#include <hip/hip_runtime.h>

#define N_NODES 50000
#define N_EDGES 800000
#define IN_DIM  162
#define HID     256
#define KPAD1   192   // IN_DIM padded to multiple of 32
#define NB      ((N_NODES + 255) / 256)   // 196 scan blocks

typedef __bf16 bf16;
typedef __bf16 bf16x8 __attribute__((ext_vector_type(8)));
typedef __bf16 bf16x4 __attribute__((ext_vector_type(4)));
typedef float  f32x4  __attribute__((ext_vector_type(4)));
typedef float  f32x8  __attribute__((ext_vector_type(8)));
typedef float  f32x16 __attribute__((ext_vector_type(16)));

#define GLDS16(g, l) __builtin_amdgcn_global_load_lds( \
    (const __attribute__((address_space(1))) void*)(g), \
    (__attribute__((address_space(3))) void*)(l), 16, 0, 0)

// ---------------------------------------------------------------------------
// All 4 weight transposes in one launch. W[K][HID] f32 -> Wt[HID][KPAD] bf16.
__device__ __forceinline__ void wt_one(const float* W, bf16* Wt, int K, int KPAD, int idx)
{
    int n = idx / KPAD;
    int k = idx - n * KPAD;
    Wt[idx] = (k < K) ? (bf16)W[(size_t)k * HID + n] : (bf16)0.0f;
}

__global__ void wt_transpose_all(const float* __restrict__ m1aw, const float* __restrict__ m1bw,
                                 const float* __restrict__ m2aw, const float* __restrict__ m2bw,
                                 bf16* __restrict__ Wt1, bf16* __restrict__ Wt2,
                                 bf16* __restrict__ Wt3, bf16* __restrict__ Wt4)
{
    const int R1 = HID * KPAD1;
    const int R2 = HID * HID;
    int idx = blockIdx.x * blockDim.x + threadIdx.x;
    if (idx < R1)                 wt_one(m1aw, Wt1, IN_DIM, KPAD1, idx);
    else if (idx < R1 + R2)       wt_one(m1bw, Wt2, HID, HID, idx - R1);
    else if (idx < R1 + 2 * R2)   wt_one(m2aw, Wt3, HID, HID, idx - R1 - R2);
    else if (idx < R1 + 3 * R2)   wt_one(m2bw, Wt4, HID, HID, idx - R1 - 2 * R2);
}

// ---------------------------------------------------------------------------
// feat f32 [N, IN_DIM] -> featbf bf16 TILED [8][N][24] (cols >= IN_DIM zeroed).
// Group g owns cols [24g, 24g+24) stored contiguously (2.4 MB per group).
__global__ void feat_to_bf16(const float* __restrict__ feat, bf16* __restrict__ featbf)
{
    int idx = blockIdx.x * blockDim.x + threadIdx.x;  // over N*KPAD1/4
    int r = idx / (KPAD1 / 4);
    int c4 = (idx - r * (KPAD1 / 4)) * 4;
    if (r >= N_NODES) return;
    bf16x4 o;
#pragma unroll
    for (int j = 0; j < 4; ++j) {
        int c = c4 + j;
        o[j] = (c < IN_DIM) ? (bf16)feat[(size_t)r * IN_DIM + c] : (bf16)0.0f;
    }
    int gch = c4 / 24;
    int off = c4 - gch * 24;
    *(bf16x4*)(featbf + ((size_t)gch * N_NODES + r) * 24 + off) = o;
}

// ---------------------------------------------------------------------------
// colsum8[b&7][c] += partial column sums of feat (reads original f32 feat).
__global__ void colsum_feat8(const float* __restrict__ feat, float* __restrict__ colsum8)
{
    int c  = threadIdx.x;
    int r0 = blockIdx.x * 50;
    if (c >= IN_DIM) return;
    float acc = 0.0f;
#pragma unroll 2
    for (int i = 0; i < 50; ++i) {
        int r = r0 + i;
        if (r < N_NODES) acc += feat[(size_t)r * IN_DIM + c];
    }
    atomicAdd(&colsum8[(blockIdx.x & 7) * KPAD1 + c], acc);
}

// ---------------------------------------------------------------------------
// CSR build.
__global__ void degree_hist(const int* __restrict__ dst, int* __restrict__ deg)
{
    int e = blockIdx.x * blockDim.x + threadIdx.x;
    atomicAdd(&deg[dst[e]], 1);
}

__global__ void block_degsum(const int* __restrict__ deg, int* __restrict__ bsum)
{
    __shared__ int s[256];
    int t = threadIdx.x;
    int idx = blockIdx.x * 256 + t;
    int v = (idx < N_NODES) ? deg[idx] : 0;
    s[t] = v;
    __syncthreads();
    for (int off = 128; off > 0; off >>= 1) {
        if (t < off) s[t] += s[t + off];
        __syncthreads();
    }
    if (t == 0) bsum[blockIdx.x] = s[0];
}

__global__ void scan_bsum(const int* __restrict__ bsum, int* __restrict__ gsum)
{
    __shared__ int s[256];
    int t = threadIdx.x;
    int v = (t < NB) ? bsum[t] : 0;
    s[t] = v;
    __syncthreads();
    for (int off = 1; off < 256; off <<= 1) {
        int u = (t >= off) ? s[t - off] : 0;
        __syncthreads();
        s[t] += u;
        __syncthreads();
    }
    gsum[t] = s[t] - v;
}

__global__ void block_scan_write(const int* __restrict__ deg, const int* __restrict__ gsum,
                                 int* __restrict__ rowptr, int* __restrict__ cursor)
{
    __shared__ int s[256];
    int t = threadIdx.x;
    int idx = blockIdx.x * 256 + t;
    int v = (idx < N_NODES) ? deg[idx] : 0;
    s[t] = v;
    __syncthreads();
    for (int off = 1; off < 256; off <<= 1) {
        int u = (t >= off) ? s[t - off] : 0;
        __syncthreads();
        s[t] += u;
        __syncthreads();
    }
    int excl = s[t] - v + gsum[blockIdx.x];
    if (idx < N_NODES) {
        rowptr[idx] = excl;
        cursor[idx] = excl;
    }
    if (idx == 0) rowptr[N_NODES] = N_EDGES;
}

__global__ void csr_fill(const int* __restrict__ src, const int* __restrict__ dst,
                         int* __restrict__ cursor, int* __restrict__ csr_src)
{
    int e = blockIdx.x * blockDim.x + threadIdx.x;
    int p = atomicAdd(&cursor[dst[e]], 1);
    csr_src[p] = src[e];
}

// ---------------------------------------------------------------------------
// Tiled gather, layer 1. featbf/xsum are [8][N][24] bf16.
// Block b: group g = b&7 -> XCD g (round-robin). Group slice = 2.4 MB, L2-fits.
// Wave = 4 nodes; per node 4 edge-stripes x 4 chunk-lanes (c4<3 active, 48B).
// 4x stripe unroll -> up to 16 independent row loads in flight per wave.
__global__ void gather1ts(const bf16* __restrict__ featbf,
                          const int* __restrict__ rowptr,
                          const int* __restrict__ csr_src,
                          bf16* __restrict__ xsum)
{
    const int g    = blockIdx.x & 7;
    const int tile = blockIdx.x >> 3;
    const int wv   = threadIdx.x >> 6;
    const int lane = threadIdx.x & 63;
    const int q    = lane >> 4;          // node within wave 0..3
    const int e    = (lane >> 2) & 3;    // edge stripe 0..3
    const int c4   = lane & 3;           // 16B chunk; c4<3 active (48B)
    const int n    = tile * 16 + wv * 4 + q;
    const bool valid = (n < N_NODES);
    const bool act   = valid && (c4 < 3);
    const int  ce    = c4 * 8;
    const bf16* base = featbf + (size_t)g * N_NODES * 24;

    f32x8 acc;
#pragma unroll
    for (int j = 0; j < 8; ++j) acc[j] = 0.0f;
    if (act && e == 0) {
        bf16x8 t0 = *(const bf16x8*)(base + (size_t)n * 24 + ce);
#pragma unroll
        for (int j = 0; j < 8; ++j) acc[j] = (float)t0[j];
    }

    int jj = valid ? rowptr[n] + e : 0;
    int je = valid ? rowptr[n + 1] : 0;
    for (; jj + 12 < je; jj += 16) {
        int s0 = __builtin_nontemporal_load(csr_src + jj);
        int s1 = __builtin_nontemporal_load(csr_src + jj + 4);
        int s2 = __builtin_nontemporal_load(csr_src + jj + 8);
        int s3 = __builtin_nontemporal_load(csr_src + jj + 12);
        if (c4 < 3) {
            bf16x8 u0 = *(const bf16x8*)(base + (size_t)s0 * 24 + ce);
            bf16x8 u1 = *(const bf16x8*)(base + (size_t)s1 * 24 + ce);
            bf16x8 u2 = *(const bf16x8*)(base + (size_t)s2 * 24 + ce);
            bf16x8 u3 = *(const bf16x8*)(base + (size_t)s3 * 24 + ce);
#pragma unroll
            for (int t = 0; t < 8; ++t)
                acc[t] += ((float)u0[t] + (float)u1[t]) + ((float)u2[t] + (float)u3[t]);
        }
    }
    for (; jj < je; jj += 4) {
        int s = __builtin_nontemporal_load(csr_src + jj);
        if (c4 < 3) {
            bf16x8 u = *(const bf16x8*)(base + (size_t)s * 24 + ce);
#pragma unroll
            for (int t = 0; t < 8; ++t) acc[t] += (float)u[t];
        }
    }

#pragma unroll
    for (int t = 0; t < 8; ++t) {
        acc[t] += __shfl_xor(acc[t], 4, 64);
        acc[t] += __shfl_xor(acc[t], 8, 64);
    }

    if (act && e == 0) {
        bf16x8 o;
#pragma unroll
        for (int t = 0; t < 8; ++t) o[t] = (bf16)acc[t];
        __builtin_nontemporal_store(o,
            (bf16x8*)(xsum + ((size_t)g * N_NODES + n) * 24 + ce));
    }
}

// ---------------------------------------------------------------------------
// Tiled gather, layer 2. node1/y2 are [8][N][32] bf16 (3.2 MB per group).
// Same wave decomposition; all 4 chunk lanes active (64B slice).
__global__ void gather2ts(const bf16* __restrict__ node1,
                          const int* __restrict__ rowptr,
                          const int* __restrict__ csr_src,
                          bf16* __restrict__ y2)
{
    const int g    = blockIdx.x & 7;
    const int tile = blockIdx.x >> 3;
    const int wv   = threadIdx.x >> 6;
    const int lane = threadIdx.x & 63;
    const int q    = lane >> 4;
    const int e    = (lane >> 2) & 3;
    const int c4   = lane & 3;
    const int n    = tile * 16 + wv * 4 + q;
    const bool valid = (n < N_NODES);
    const int  ce    = c4 * 8;
    const bf16* base = node1 + (size_t)g * N_NODES * 32;

    f32x8 acc;
#pragma unroll
    for (int j = 0; j < 8; ++j) acc[j] = 0.0f;
    if (valid && e == 0) {
        bf16x8 t0 = *(const bf16x8*)(base + (size_t)n * 32 + ce);
#pragma unroll
        for (int j = 0; j < 8; ++j) acc[j] = (float)t0[j];
    }

    int jj = valid ? rowptr[n] + e : 0;
    int je = valid ? rowptr[n + 1] : 0;
    for (; jj + 12 < je; jj += 16) {
        int s0 = __builtin_nontemporal_load(csr_src + jj);
        int s1 = __builtin_nontemporal_load(csr_src + jj + 4);
        int s2 = __builtin_nontemporal_load(csr_src + jj + 8);
        int s3 = __builtin_nontemporal_load(csr_src + jj + 12);
        bf16x8 u0 = *(const bf16x8*)(base + (size_t)s0 * 32 + ce);
        bf16x8 u1 = *(const bf16x8*)(base + (size_t)s1 * 32 + ce);
        bf16x8 u2 = *(const bf16x8*)(base + (size_t)s2 * 32 + ce);
        bf16x8 u3 = *(const bf16x8*)(base + (size_t)s3 * 32 + ce);
#pragma unroll
        for (int t = 0; t < 8; ++t)
            acc[t] += ((float)u0[t] + (float)u1[t]) + ((float)u2[t] + (float)u3[t]);
    }
    for (; jj < je; jj += 4) {
        int s = __builtin_nontemporal_load(csr_src + jj);
        bf16x8 u = *(const bf16x8*)(base + (size_t)s * 32 + ce);
#pragma unroll
        for (int t = 0; t < 8; ++t) acc[t] += (float)u[t];
    }

#pragma unroll
    for (int t = 0; t < 8; ++t) {
        acc[t] += __shfl_xor(acc[t], 4, 64);
        acc[t] += __shfl_xor(acc[t], 8, 64);
    }

    if (valid && e == 0) {
        bf16x8 o;
#pragma unroll
        for (int t = 0; t < 8; ++t) o[t] = (bf16)acc[t];
        __builtin_nontemporal_store(o,
            (bf16x8*)(y2 + ((size_t)g * N_NODES + n) * 32 + ce));
    }
}

// ---------------------------------------------------------------------------
// GEMM v2 (+ optional fused column-sum of the post-relu output).
// ACHUNK: 0 = X linear [M][KPAD]; else X tiled [KPAD/ACHUNK][N_NODES][ACHUNK].
// OCHUNK: 0 = out linear [M][HID]; else out tiled [HID/32][N_NODES][32].
template<int KPAD, int ACHUNK, int OCHUNK>
__launch_bounds__(256)
__global__ void gemm_relu2(const bf16* __restrict__ X,
                           const bf16* __restrict__ Wt,
                           const float* __restrict__ bias,
                           bf16* __restrict__ out_bf,
                           float* __restrict__ colsum,   // nullable
                           int M)
{
    __shared__ __align__(128) bf16 sB[8192];   // 16 KB
    __shared__ float cs[256];

    const int tid  = threadIdx.x;
    const int w    = tid >> 6;
    const int lane = tid & 63;
    const int p    = lane >> 5;
    const int cn   = lane & 31;
    const int m_base = blockIdx.x * 128 + w * 32;

    int arow = m_base + cn;
    if (arow >= M) arow = M - 1;   // clamp (stores guarded)

    f32x16 acc[8];
#pragma unroll
    for (int j = 0; j < 8; ++j)
#pragma unroll
        for (int r = 0; r < 16; ++r) acc[j][r] = 0.0f;

    for (int k0 = 0; k0 < KPAD; k0 += 32) {
        __syncthreads();
#pragma unroll
        for (int i = 0; i < 4; ++i) {
            int fb = w * 4 + i;
            int j  = fb >> 1;
            int kk = fb & 1;
            const bf16* g = Wt + (size_t)(j * 32 + cn) * KPAD + k0 + kk * 16 + p * 8;
            GLDS16(g, sB + fb * 512);
        }
        __syncthreads();

#pragma unroll
        for (int kk = 0; kk < 2; ++kk) {
            bf16x8 a;
            if constexpr (ACHUNK == 0) {
                a = *(const bf16x8*)(X + (size_t)arow * KPAD + k0 + kk * 16 + p * 8);
            } else {
                const int e   = k0 + kk * 16 + p * 8;
                const int gch = e / ACHUNK;
                const int off = e - gch * ACHUNK;
                a = *(const bf16x8*)(X + ((size_t)gch * N_NODES + arow) * ACHUNK + off);
            }
#pragma unroll
            for (int j = 0; j < 8; ++j) {
                bf16x8 b = *(const bf16x8*)(sB + (j * 2 + kk) * 512 + lane * 8);
                acc[j] = __builtin_amdgcn_mfma_f32_32x32x16_bf16(a, b, acc[j], 0, 0, 0);
            }
        }
    }

    if (colsum) {
        cs[tid] = 0.0f;
        __syncthreads();
    }

#pragma unroll
    for (int j = 0; j < 8; ++j) {
        const int col = j * 32 + cn;
        const float bv = bias[col];
        float part = 0.0f;
#pragma unroll
        for (int r = 0; r < 16; ++r) {
            int rl = (r & 3) + 8 * (r >> 2) + 4 * p;
            int mo = m_base + rl;
            if (mo < M) {
                float v = acc[j][r] + bv;
                v = v > 0.0f ? v : 0.0f;
                if constexpr (OCHUNK == 0)
                    out_bf[(size_t)mo * HID + col] = (bf16)v;
                else
                    out_bf[((size_t)j * N_NODES + mo) * OCHUNK + cn] = (bf16)v;
                part += v;
            }
        }
        if (colsum) {
            part += __shfl_xor(part, 32, 64);   // combine the two p-halves
            if (p == 0) atomicAdd(&cs[col], part);
        }
    }

    if (colsum) {
        __syncthreads();
        atomicAdd(&colsum[tid], cs[tid]);
    }
}

// ---------------------------------------------------------------------------
// Graph head: three GEMVs + sum + final GEMV, single block of 256 threads.
__global__ void graph_head(const float* __restrict__ cs0_8,
                           const float* __restrict__ cs1,
                           const float* __restrict__ cs2,
                           const float* __restrict__ g0w, const float* __restrict__ g0b,
                           const float* __restrict__ g1w, const float* __restrict__ g1b,
                           const float* __restrict__ g2w, const float* __restrict__ g2b,
                           const float* __restrict__ glw, const float* __restrict__ glb,
                           float* __restrict__ gvec)
{
    __shared__ float v0[IN_DIM], v1[HID], v2[HID], gs[HID];
    int t = threadIdx.x;
    if (t < IN_DIM) {
        float s = 0.0f;
#pragma unroll
        for (int i = 0; i < 8; ++i) s += cs0_8[i * KPAD1 + t];
        v0[t] = s;
    }
    v1[t] = cs1[t];
    v2[t] = cs2[t];
    __syncthreads();

    float a0 = 0.0f, a1 = 0.0f, a2 = 0.0f;
    for (int k = 0; k < IN_DIM; ++k) a0 += v0[k] * g0w[k * HID + t];
    for (int k = 0; k < HID; ++k) {
        a1 += v1[k] * g1w[k * HID + t];
        a2 += v2[k] * g2w[k * HID + t];
    }
    float e0 = fmaxf(a0 + g0b[t], 0.0f);
    float e1 = fmaxf(a1 + g1b[t], 0.0f);
    float e2 = fmaxf(a2 + g2b[t], 0.0f);
    gs[t] = e0 + e1 + e2;
    __syncthreads();

    float a3 = 0.0f;
    for (int k = 0; k < HID; ++k) a3 += gs[k] * glw[k * HID + t];
    gvec[t] = fmaxf(a3 + glb[t], 0.0f);
}

// ---------------------------------------------------------------------------
// out[n,c] = node2[n,c](bf16) + gvec[c] (f32 out); 4 elements per thread.
__global__ void final_add(const bf16* __restrict__ node2,
                          const float* __restrict__ gvec,
                          float* __restrict__ out)
{
    int idx = blockIdx.x * blockDim.x + threadIdx.x;
    size_t base = (size_t)idx * 4;
    int c = (int)(base & (HID - 1));
    bf16x4 v = *(const bf16x4*)(node2 + base);
    f32x4 g = *(const f32x4*)(gvec + c);
    f32x4 o;
#pragma unroll
    for (int j = 0; j < 4; ++j) o[j] = (float)v[j] + g[j];
    *(f32x4*)(out + base) = o;
}

// ---------------------------------------------------------------------------
extern "C" void kernel_launch(void* const* d_in, const int* in_sizes, int n_in,
                              void* d_out, int out_size, void* d_ws, size_t ws_size,
                              hipStream_t stream)
{
    const float* feat = (const float*)d_in[0];
    const int*   ei   = (const int*)d_in[1];
    const int*   src  = ei;
    const int*   dst  = ei + N_EDGES;
    const float* g0w = (const float*)d_in[2],  *g0b = (const float*)d_in[3];
    const float* g1w = (const float*)d_in[4],  *g1b = (const float*)d_in[5];
    const float* g2w = (const float*)d_in[6],  *g2b = (const float*)d_in[7];
    const float* glw = (const float*)d_in[8],  *glb = (const float*)d_in[9];
    const float* m1aw = (const float*)d_in[10], *m1ab = (const float*)d_in[11];
    const float* m1bw = (const float*)d_in[12], *m1bb = (const float*)d_in[13];
    const float* m2aw = (const float*)d_in[14], *m2ab = (const float*)d_in[15];
    const float* m2bw = (const float*)d_in[16], *m2bb = (const float*)d_in[17];
    float* out = (float*)d_out;

    char* ws = (char*)d_ws;
    size_t off = 0;
    auto alloc = [&](size_t bytes) -> void* {
        void* p = ws + off;
        off += (bytes + 255) & ~(size_t)255;
        return p;
    };
    bf16*  featbf = (bf16*)alloc((size_t)N_NODES * KPAD1 * 2);   // tiled [8][N][24]
    bf16*  xsum  = (bf16*) alloc((size_t)N_NODES * KPAD1 * 2);   // tiled [8][N][24]
    bf16*  y2    = (bf16*) alloc((size_t)N_NODES * HID * 2);     // tiled [8][N][32]
    bf16*  node2 = (bf16*) alloc((size_t)N_NODES * HID * 2);     // linear
    bf16*  h1    = (bf16*) alloc((size_t)N_NODES * HID * 2);     // linear (reused as h2)
    bf16*  node1 = (bf16*) alloc((size_t)N_NODES * HID * 2);     // tiled [8][N][32]
    bf16*  Wt1   = (bf16*) alloc((size_t)HID * KPAD1 * 2);
    bf16*  Wt2   = (bf16*) alloc((size_t)HID * HID * 2);
    bf16*  Wt3   = (bf16*) alloc((size_t)HID * HID * 2);
    bf16*  Wt4   = (bf16*) alloc((size_t)HID * HID * 2);
    int*   deg     = (int*)alloc((size_t)N_NODES * 4);
    int*   rowptr  = (int*)alloc((size_t)(N_NODES + 1) * 4);
    int*   cursor  = (int*)alloc((size_t)N_NODES * 4);
    int*   csr_src = (int*)alloc((size_t)N_EDGES * 4);
    int*   bsum    = (int*)alloc(256 * 4);
    int*   gsum    = (int*)alloc(256 * 4);
    float* csums   = (float*)alloc((8 * KPAD1 + 256 + 256 + 256) * 4);
    float* colsum0_8 = csums;                    // 8 x 192 partial slots
    float* colsum1   = csums + 8 * KPAD1;        // 256
    float* colsum2   = csums + 8 * KPAD1 + 256;  // 256
    float* gvec      = csums + 8 * KPAD1 + 512;  // 256

    hipMemsetAsync(csums, 0, (8 * KPAD1 + 512) * 4, stream);
    hipMemsetAsync(deg, 0, (size_t)N_NODES * 4, stream);

    // all 4 weight transposes, one launch
    wt_transpose_all<<<(HID * KPAD1 + 3 * HID * HID + 255) / 256, 256, 0, stream>>>(
        m1aw, m1bw, m2aw, m2bw, Wt1, Wt2, Wt3, Wt4);

    // feat -> bf16 tiled
    feat_to_bf16<<<((size_t)N_NODES * (KPAD1 / 4) + 255) / 256, 256, 0, stream>>>(feat, featbf);
    // colsum0 partials (8-slot spread)
    colsum_feat8<<<1000, 192, 0, stream>>>(feat, colsum0_8);

    // CSR build (grouped by dst)
    degree_hist<<<N_EDGES / 256, 256, 0, stream>>>(dst, deg);
    block_degsum<<<NB, 256, 0, stream>>>(deg, bsum);
    scan_bsum<<<1, 256, 0, stream>>>(bsum, gsum);
    block_scan_write<<<NB, 256, 0, stream>>>(deg, gsum, rowptr, cursor);
    csr_fill<<<N_EDGES / 256, 256, 0, stream>>>(src, dst, cursor, csr_src);

    const int gtiles = (N_NODES + 15) / 16;   // 4 nodes/wave x 4 waves
    // xsum = bf16(feat + gather(feat)) — tiled, XCD-pinned, 4-stripe MLP
    gather1ts<<<gtiles * 8, 256, 0, stream>>>(featbf, rowptr, csr_src, xsum);

    const int gblocks = (N_NODES + 127) / 128;
    // h1 = relu(xsum @ m1a_w + b)          (A tiled24 -> linear out)
    gemm_relu2<KPAD1, 24, 0><<<gblocks, 256, 0, stream>>>(xsum, Wt1, m1ab, h1, nullptr, N_NODES);
    // node1 = relu(h1 @ m1b_w + b), colsum1 fused   (linear A -> tiled32 out)
    gemm_relu2<HID, 0, 32><<<gblocks, 256, 0, stream>>>(h1, Wt2, m1bb, node1, colsum1, N_NODES);
    // y2 = bf16(node1 + gather(node1)) — tiled, XCD-pinned, 4-stripe MLP
    gather2ts<<<gtiles * 8, 256, 0, stream>>>(node1, rowptr, csr_src, y2);
    // h2 = relu(y2 @ m2a_w + b)  (reuse h1 buffer)  (A tiled32 -> linear out)
    gemm_relu2<HID, 32, 0><<<gblocks, 256, 0, stream>>>(y2, Wt3, m2ab, h1, nullptr, N_NODES);
    // node2 = relu(h2 @ m2b_w + b), colsum2 fused   (linear A -> linear out)
    gemm_relu2<HID, 0, 0><<<gblocks, 256, 0, stream>>>(h1, Wt4, m2bb, node2, colsum2, N_NODES);
    // graph head -> gvec = g_last
    graph_head<<<1, 256, 0, stream>>>(colsum0_8, colsum1, colsum2,
                                      g0w, g0b, g1w, g1b, g2w, g2b, glw, glb, gvec);
    // out = node2 + gvec
    final_add<<<((size_t)N_NODES * HID / 4 + 255) / 256, 256, 0, stream>>>(node2, gvec, out);
    (void)in_sizes; (void)n_in; (void)out_size; (void)ws_size;
}

// Round 5
// 541.256 us; speedup vs baseline: 1.4376x; 1.1227x over previous
//
#include <hip/hip_runtime.h>

#define N_NODES 50000
#define N_EDGES 800000
#define IN_DIM  162
#define HID     256
#define KPAD1   192   // IN_DIM padded to multiple of 32
#define NB      ((N_NODES + 255) / 256)   // 196 scan blocks

typedef __bf16 bf16;
typedef __bf16 bf16x8 __attribute__((ext_vector_type(8)));
typedef __bf16 bf16x4 __attribute__((ext_vector_type(4)));
typedef float  f32x4  __attribute__((ext_vector_type(4)));
typedef float  f32x8  __attribute__((ext_vector_type(8)));
typedef float  f32x16 __attribute__((ext_vector_type(16)));

#define GLDS16(g, l) __builtin_amdgcn_global_load_lds( \
    (const __attribute__((address_space(1))) void*)(g), \
    (__attribute__((address_space(3))) void*)(l), 16, 0, 0)

// ---------------------------------------------------------------------------
// All 4 weight transposes in one launch. W[K][HID] f32 -> Wt[HID][KPAD] bf16.
__device__ __forceinline__ void wt_one(const float* W, bf16* Wt, int K, int KPAD, int idx)
{
    int n = idx / KPAD;
    int k = idx - n * KPAD;
    Wt[idx] = (k < K) ? (bf16)W[(size_t)k * HID + n] : (bf16)0.0f;
}

__global__ void wt_transpose_all(const float* __restrict__ m1aw, const float* __restrict__ m1bw,
                                 const float* __restrict__ m2aw, const float* __restrict__ m2bw,
                                 bf16* __restrict__ Wt1, bf16* __restrict__ Wt2,
                                 bf16* __restrict__ Wt3, bf16* __restrict__ Wt4)
{
    const int R1 = HID * KPAD1;
    const int R2 = HID * HID;
    int idx = blockIdx.x * blockDim.x + threadIdx.x;
    if (idx < R1)                 wt_one(m1aw, Wt1, IN_DIM, KPAD1, idx);
    else if (idx < R1 + R2)       wt_one(m1bw, Wt2, HID, HID, idx - R1);
    else if (idx < R1 + 2 * R2)   wt_one(m2aw, Wt3, HID, HID, idx - R1 - R2);
    else if (idx < R1 + 3 * R2)   wt_one(m2bw, Wt4, HID, HID, idx - R1 - 2 * R2);
}

// ---------------------------------------------------------------------------
// feat f32 [N, IN_DIM] -> featbf bf16 TILED [8][N][24] (cols >= IN_DIM zeroed).
// Group g owns cols [24g, 24g+24) stored contiguously (2.4 MB per group).
__global__ void feat_to_bf16(const float* __restrict__ feat, bf16* __restrict__ featbf)
{
    int idx = blockIdx.x * blockDim.x + threadIdx.x;  // over N*KPAD1/4
    int r = idx / (KPAD1 / 4);
    int c4 = (idx - r * (KPAD1 / 4)) * 4;
    if (r >= N_NODES) return;
    bf16x4 o;
#pragma unroll
    for (int j = 0; j < 4; ++j) {
        int c = c4 + j;
        o[j] = (c < IN_DIM) ? (bf16)feat[(size_t)r * IN_DIM + c] : (bf16)0.0f;
    }
    int gch = c4 / 24;
    int off = c4 - gch * 24;
    *(bf16x4*)(featbf + ((size_t)gch * N_NODES + r) * 24 + off) = o;
}

// ---------------------------------------------------------------------------
// colsum8[b&7][c] += partial column sums of feat (reads original f32 feat).
__global__ void colsum_feat8(const float* __restrict__ feat, float* __restrict__ colsum8)
{
    int c  = threadIdx.x;
    int r0 = blockIdx.x * 50;
    if (c >= IN_DIM) return;
    float acc = 0.0f;
#pragma unroll 2
    for (int i = 0; i < 50; ++i) {
        int r = r0 + i;
        if (r < N_NODES) acc += feat[(size_t)r * IN_DIM + c];
    }
    atomicAdd(&colsum8[(blockIdx.x & 7) * KPAD1 + c], acc);
}

// ---------------------------------------------------------------------------
// CSR build.
__global__ void degree_hist(const int* __restrict__ dst, int* __restrict__ deg)
{
    int e = blockIdx.x * blockDim.x + threadIdx.x;
    atomicAdd(&deg[dst[e]], 1);
}

__global__ void block_degsum(const int* __restrict__ deg, int* __restrict__ bsum)
{
    __shared__ int s[256];
    int t = threadIdx.x;
    int idx = blockIdx.x * 256 + t;
    int v = (idx < N_NODES) ? deg[idx] : 0;
    s[t] = v;
    __syncthreads();
    for (int off = 128; off > 0; off >>= 1) {
        if (t < off) s[t] += s[t + off];
        __syncthreads();
    }
    if (t == 0) bsum[blockIdx.x] = s[0];
}

__global__ void scan_bsum(const int* __restrict__ bsum, int* __restrict__ gsum)
{
    __shared__ int s[256];
    int t = threadIdx.x;
    int v = (t < NB) ? bsum[t] : 0;
    s[t] = v;
    __syncthreads();
    for (int off = 1; off < 256; off <<= 1) {
        int u = (t >= off) ? s[t - off] : 0;
        __syncthreads();
        s[t] += u;
        __syncthreads();
    }
    gsum[t] = s[t] - v;
}

__global__ void block_scan_write(const int* __restrict__ deg, const int* __restrict__ gsum,
                                 int* __restrict__ rowptr, int* __restrict__ cursor)
{
    __shared__ int s[256];
    int t = threadIdx.x;
    int idx = blockIdx.x * 256 + t;
    int v = (idx < N_NODES) ? deg[idx] : 0;
    s[t] = v;
    __syncthreads();
    for (int off = 1; off < 256; off <<= 1) {
        int u = (t >= off) ? s[t - off] : 0;
        __syncthreads();
        s[t] += u;
        __syncthreads();
    }
    int excl = s[t] - v + gsum[blockIdx.x];
    if (idx < N_NODES) {
        rowptr[idx] = excl;
        cursor[idx] = excl;
    }
    if (idx == 0) rowptr[N_NODES] = N_EDGES;
}

__global__ void csr_fill(const int* __restrict__ src, const int* __restrict__ dst,
                         int* __restrict__ cursor, int* __restrict__ csr_src)
{
    int e = blockIdx.x * blockDim.x + threadIdx.x;
    int p = atomicAdd(&cursor[dst[e]], 1);
    csr_src[p] = src[e];
}

// ---------------------------------------------------------------------------
// Gather v5: tiled [8][N][CHUNK] input/output, XCD-pinned groups, in-register
// index list, masked unrolled row-load blocks (no per-edge idx latency, no
// serial tail for deg <= 32).
// Wave = 4 nodes; per node: lane j = e*4+c4 (4 stripes x 4 chunks).
// Stripe e handles list positions {4e..4e+3} (block1) and {16+4e..16+4e+3}
// (block2, per-stripe gated); deg>32 -> rare stride-4 loop.
// Loads are unconditional (clamped csr_src values are valid node ids);
// only the accumulates are predicated on p < deg.
template<int CHUNK, int NACT>
__launch_bounds__(256)
__global__ void gather_v5(const bf16* __restrict__ xin,
                          const int* __restrict__ rowptr,
                          const int* __restrict__ csr_src,
                          bf16* __restrict__ xout)
{
    const int g    = blockIdx.x & 7;
    const int tile = blockIdx.x >> 3;
    const int wv   = threadIdx.x >> 6;
    const int lane = threadIdx.x & 63;
    const int q    = lane >> 4;          // node within wave 0..3
    const int j    = lane & 15;          // idx slot
    const int e    = j >> 2;             // stripe 0..3
    const int c4   = j & 3;              // 16B chunk
    const int n    = tile * 16 + wv * 4 + q;
    const bool valid = (n < N_NODES);
    const bool act   = (c4 < NACT);
    const int  ce    = c4 * 8;
    const bf16* base = xin + (size_t)g * N_NODES * CHUNK;

    int r0 = 0, deg = 0;
    if (valid) {
        r0  = rowptr[n];
        deg = rowptr[n + 1] - r0;
    }

    // coalesced index prefetch: positions j and 16+j of this node's list
    int a0 = r0 + j;        if (a0 > N_EDGES - 1) a0 = N_EDGES - 1;
    int a1 = r0 + 16 + j;   if (a1 > N_EDGES - 1) a1 = N_EDGES - 1;
    const int i0 = csr_src[a0];
    const int i1 = csr_src[a1];

    f32x8 acc;
#pragma unroll
    for (int t = 0; t < 8; ++t) acc[t] = 0.0f;
    if (valid && e == 0 && act) {
        bf16x8 t0 = *(const bf16x8*)(base + (size_t)n * CHUNK + ce);
#pragma unroll
        for (int t = 0; t < 8; ++t) acc[t] = (float)t0[t];
    }

    const int lb = lane & ~3;   // first lane of this (q,e) quad

    // ---- block 1: positions 4e + k, k = 0..3 (covers deg <= 16) ----
    {
        const int s0 = __shfl(i0, lb + 0, 64);
        const int s1 = __shfl(i0, lb + 1, 64);
        const int s2 = __shfl(i0, lb + 2, 64);
        const int s3 = __shfl(i0, lb + 3, 64);
        const int p0 = 4 * e;
        if (act) {
            bf16x8 u0 = *(const bf16x8*)(base + (size_t)s0 * CHUNK + ce);
            bf16x8 u1 = *(const bf16x8*)(base + (size_t)s1 * CHUNK + ce);
            bf16x8 u2 = *(const bf16x8*)(base + (size_t)s2 * CHUNK + ce);
            bf16x8 u3 = *(const bf16x8*)(base + (size_t)s3 * CHUNK + ce);
            if (p0 + 0 < deg) {
#pragma unroll
                for (int t = 0; t < 8; ++t) acc[t] += (float)u0[t];
            }
            if (p0 + 1 < deg) {
#pragma unroll
                for (int t = 0; t < 8; ++t) acc[t] += (float)u1[t];
            }
            if (p0 + 2 < deg) {
#pragma unroll
                for (int t = 0; t < 8; ++t) acc[t] += (float)u2[t];
            }
            if (p0 + 3 < deg) {
#pragma unroll
                for (int t = 0; t < 8; ++t) acc[t] += (float)u3[t];
            }
        }
    }

    // ---- block 2: positions 16 + 4e + k (covers deg <= 32), stripe-gated ----
    {
        const int s0 = __shfl(i1, lb + 0, 64);
        const int s1 = __shfl(i1, lb + 1, 64);
        const int s2 = __shfl(i1, lb + 2, 64);
        const int s3 = __shfl(i1, lb + 3, 64);
        const int p0 = 16 + 4 * e;
        if (act && p0 < deg) {
            bf16x8 u0 = *(const bf16x8*)(base + (size_t)s0 * CHUNK + ce);
            bf16x8 u1 = *(const bf16x8*)(base + (size_t)s1 * CHUNK + ce);
            bf16x8 u2 = *(const bf16x8*)(base + (size_t)s2 * CHUNK + ce);
            bf16x8 u3 = *(const bf16x8*)(base + (size_t)s3 * CHUNK + ce);
            {
#pragma unroll
                for (int t = 0; t < 8; ++t) acc[t] += (float)u0[t];
            }
            if (p0 + 1 < deg) {
#pragma unroll
                for (int t = 0; t < 8; ++t) acc[t] += (float)u1[t];
            }
            if (p0 + 2 < deg) {
#pragma unroll
                for (int t = 0; t < 8; ++t) acc[t] += (float)u2[t];
            }
            if (p0 + 3 < deg) {
#pragma unroll
                for (int t = 0; t < 8; ++t) acc[t] += (float)u3[t];
            }
        }
    }

    // ---- rare tail: deg > 32 ----
    for (int p = 32 + e; p < deg; p += 4) {
        const int s = csr_src[r0 + p];
        if (act) {
            bf16x8 u = *(const bf16x8*)(base + (size_t)s * CHUNK + ce);
#pragma unroll
            for (int t = 0; t < 8; ++t) acc[t] += (float)u[t];
        }
    }

    // reduce across stripes (lanes differing in bits 2..3)
#pragma unroll
    for (int t = 0; t < 8; ++t) {
        acc[t] += __shfl_xor(acc[t], 4, 64);
        acc[t] += __shfl_xor(acc[t], 8, 64);
    }

    if (valid && e == 0 && act) {
        bf16x8 o;
#pragma unroll
        for (int t = 0; t < 8; ++t) o[t] = (bf16)acc[t];
        __builtin_nontemporal_store(o,
            (bf16x8*)(xout + ((size_t)g * N_NODES + n) * CHUNK + ce));
    }
}

// ---------------------------------------------------------------------------
// GEMM v2 (+ optional fused column-sum of the post-relu output).
// ACHUNK: 0 = X linear [M][KPAD]; else X tiled [KPAD/ACHUNK][N_NODES][ACHUNK].
// OCHUNK: 0 = out linear [M][HID]; else out tiled [HID/32][N_NODES][32].
template<int KPAD, int ACHUNK, int OCHUNK>
__launch_bounds__(256)
__global__ void gemm_relu2(const bf16* __restrict__ X,
                           const bf16* __restrict__ Wt,
                           const float* __restrict__ bias,
                           bf16* __restrict__ out_bf,
                           float* __restrict__ colsum,   // nullable
                           int M)
{
    __shared__ __align__(128) bf16 sB[8192];   // 16 KB
    __shared__ float cs[256];

    const int tid  = threadIdx.x;
    const int w    = tid >> 6;
    const int lane = tid & 63;
    const int p    = lane >> 5;
    const int cn   = lane & 31;
    const int m_base = blockIdx.x * 128 + w * 32;

    int arow = m_base + cn;
    if (arow >= M) arow = M - 1;   // clamp (stores guarded)

    f32x16 acc[8];
#pragma unroll
    for (int j = 0; j < 8; ++j)
#pragma unroll
        for (int r = 0; r < 16; ++r) acc[j][r] = 0.0f;

    for (int k0 = 0; k0 < KPAD; k0 += 32) {
        __syncthreads();
#pragma unroll
        for (int i = 0; i < 4; ++i) {
            int fb = w * 4 + i;
            int j  = fb >> 1;
            int kk = fb & 1;
            const bf16* g = Wt + (size_t)(j * 32 + cn) * KPAD + k0 + kk * 16 + p * 8;
            GLDS16(g, sB + fb * 512);
        }
        __syncthreads();

#pragma unroll
        for (int kk = 0; kk < 2; ++kk) {
            bf16x8 a;
            if constexpr (ACHUNK == 0) {
                a = *(const bf16x8*)(X + (size_t)arow * KPAD + k0 + kk * 16 + p * 8);
            } else {
                const int e   = k0 + kk * 16 + p * 8;
                const int gch = e / ACHUNK;
                const int off = e - gch * ACHUNK;
                a = *(const bf16x8*)(X + ((size_t)gch * N_NODES + arow) * ACHUNK + off);
            }
#pragma unroll
            for (int j = 0; j < 8; ++j) {
                bf16x8 b = *(const bf16x8*)(sB + (j * 2 + kk) * 512 + lane * 8);
                acc[j] = __builtin_amdgcn_mfma_f32_32x32x16_bf16(a, b, acc[j], 0, 0, 0);
            }
        }
    }

    if (colsum) {
        cs[tid] = 0.0f;
        __syncthreads();
    }

#pragma unroll
    for (int j = 0; j < 8; ++j) {
        const int col = j * 32 + cn;
        const float bv = bias[col];
        float part = 0.0f;
#pragma unroll
        for (int r = 0; r < 16; ++r) {
            int rl = (r & 3) + 8 * (r >> 2) + 4 * p;
            int mo = m_base + rl;
            if (mo < M) {
                float v = acc[j][r] + bv;
                v = v > 0.0f ? v : 0.0f;
                if constexpr (OCHUNK == 0)
                    out_bf[(size_t)mo * HID + col] = (bf16)v;
                else
                    out_bf[((size_t)j * N_NODES + mo) * OCHUNK + cn] = (bf16)v;
                part += v;
            }
        }
        if (colsum) {
            part += __shfl_xor(part, 32, 64);   // combine the two p-halves
            if (p == 0) atomicAdd(&cs[col], part);
        }
    }

    if (colsum) {
        __syncthreads();
        atomicAdd(&colsum[tid], cs[tid]);
    }
}

// ---------------------------------------------------------------------------
// Graph head: three GEMVs + sum + final GEMV, single block of 256 threads.
__global__ void graph_head(const float* __restrict__ cs0_8,
                           const float* __restrict__ cs1,
                           const float* __restrict__ cs2,
                           const float* __restrict__ g0w, const float* __restrict__ g0b,
                           const float* __restrict__ g1w, const float* __restrict__ g1b,
                           const float* __restrict__ g2w, const float* __restrict__ g2b,
                           const float* __restrict__ glw, const float* __restrict__ glb,
                           float* __restrict__ gvec)
{
    __shared__ float v0[IN_DIM], v1[HID], v2[HID], gs[HID];
    int t = threadIdx.x;
    if (t < IN_DIM) {
        float s = 0.0f;
#pragma unroll
        for (int i = 0; i < 8; ++i) s += cs0_8[i * KPAD1 + t];
        v0[t] = s;
    }
    v1[t] = cs1[t];
    v2[t] = cs2[t];
    __syncthreads();

    float a0 = 0.0f, a1 = 0.0f, a2 = 0.0f;
    for (int k = 0; k < IN_DIM; ++k) a0 += v0[k] * g0w[k * HID + t];
    for (int k = 0; k < HID; ++k) {
        a1 += v1[k] * g1w[k * HID + t];
        a2 += v2[k] * g2w[k * HID + t];
    }
    float e0 = fmaxf(a0 + g0b[t], 0.0f);
    float e1 = fmaxf(a1 + g1b[t], 0.0f);
    float e2 = fmaxf(a2 + g2b[t], 0.0f);
    gs[t] = e0 + e1 + e2;
    __syncthreads();

    float a3 = 0.0f;
    for (int k = 0; k < HID; ++k) a3 += gs[k] * glw[k * HID + t];
    gvec[t] = fmaxf(a3 + glb[t], 0.0f);
}

// ---------------------------------------------------------------------------
// out[n,c] = node2[n,c](bf16) + gvec[c] (f32 out); 4 elements per thread.
__global__ void final_add(const bf16* __restrict__ node2,
                          const float* __restrict__ gvec,
                          float* __restrict__ out)
{
    int idx = blockIdx.x * blockDim.x + threadIdx.x;
    size_t base = (size_t)idx * 4;
    int c = (int)(base & (HID - 1));
    bf16x4 v = *(const bf16x4*)(node2 + base);
    f32x4 g = *(const f32x4*)(gvec + c);
    f32x4 o;
#pragma unroll
    for (int j = 0; j < 4; ++j) o[j] = (float)v[j] + g[j];
    *(f32x4*)(out + base) = o;
}

// ---------------------------------------------------------------------------
extern "C" void kernel_launch(void* const* d_in, const int* in_sizes, int n_in,
                              void* d_out, int out_size, void* d_ws, size_t ws_size,
                              hipStream_t stream)
{
    const float* feat = (const float*)d_in[0];
    const int*   ei   = (const int*)d_in[1];
    const int*   src  = ei;
    const int*   dst  = ei + N_EDGES;
    const float* g0w = (const float*)d_in[2],  *g0b = (const float*)d_in[3];
    const float* g1w = (const float*)d_in[4],  *g1b = (const float*)d_in[5];
    const float* g2w = (const float*)d_in[6],  *g2b = (const float*)d_in[7];
    const float* glw = (const float*)d_in[8],  *glb = (const float*)d_in[9];
    const float* m1aw = (const float*)d_in[10], *m1ab = (const float*)d_in[11];
    const float* m1bw = (const float*)d_in[12], *m1bb = (const float*)d_in[13];
    const float* m2aw = (const float*)d_in[14], *m2ab = (const float*)d_in[15];
    const float* m2bw = (const float*)d_in[16], *m2bb = (const float*)d_in[17];
    float* out = (float*)d_out;

    char* ws = (char*)d_ws;
    size_t off = 0;
    auto alloc = [&](size_t bytes) -> void* {
        void* p = ws + off;
        off += (bytes + 255) & ~(size_t)255;
        return p;
    };
    bf16*  featbf = (bf16*)alloc((size_t)N_NODES * KPAD1 * 2);   // tiled [8][N][24]
    bf16*  xsum  = (bf16*) alloc((size_t)N_NODES * KPAD1 * 2);   // tiled [8][N][24]
    bf16*  y2    = (bf16*) alloc((size_t)N_NODES * HID * 2);     // tiled [8][N][32]
    bf16*  node2 = (bf16*) alloc((size_t)N_NODES * HID * 2);     // linear
    bf16*  h1    = (bf16*) alloc((size_t)N_NODES * HID * 2);     // linear (reused as h2)
    bf16*  node1 = (bf16*) alloc((size_t)N_NODES * HID * 2);     // tiled [8][N][32]
    bf16*  Wt1   = (bf16*) alloc((size_t)HID * KPAD1 * 2);
    bf16*  Wt2   = (bf16*) alloc((size_t)HID * HID * 2);
    bf16*  Wt3   = (bf16*) alloc((size_t)HID * HID * 2);
    bf16*  Wt4   = (bf16*) alloc((size_t)HID * HID * 2);
    int*   deg     = (int*)alloc((size_t)N_NODES * 4);
    int*   rowptr  = (int*)alloc((size_t)(N_NODES + 1) * 4);
    int*   cursor  = (int*)alloc((size_t)N_NODES * 4);
    int*   csr_src = (int*)alloc((size_t)N_EDGES * 4);
    int*   bsum    = (int*)alloc(256 * 4);
    int*   gsum    = (int*)alloc(256 * 4);
    float* csums   = (float*)alloc((8 * KPAD1 + 256 + 256 + 256) * 4);
    float* colsum0_8 = csums;                    // 8 x 192 partial slots
    float* colsum1   = csums + 8 * KPAD1;        // 256
    float* colsum2   = csums + 8 * KPAD1 + 256;  // 256
    float* gvec      = csums + 8 * KPAD1 + 512;  // 256

    hipMemsetAsync(csums, 0, (8 * KPAD1 + 512) * 4, stream);
    hipMemsetAsync(deg, 0, (size_t)N_NODES * 4, stream);

    // all 4 weight transposes, one launch
    wt_transpose_all<<<(HID * KPAD1 + 3 * HID * HID + 255) / 256, 256, 0, stream>>>(
        m1aw, m1bw, m2aw, m2bw, Wt1, Wt2, Wt3, Wt4);

    // feat -> bf16 tiled
    feat_to_bf16<<<((size_t)N_NODES * (KPAD1 / 4) + 255) / 256, 256, 0, stream>>>(feat, featbf);
    // colsum0 partials (8-slot spread)
    colsum_feat8<<<1000, 192, 0, stream>>>(feat, colsum0_8);

    // CSR build (grouped by dst)
    degree_hist<<<N_EDGES / 256, 256, 0, stream>>>(dst, deg);
    block_degsum<<<NB, 256, 0, stream>>>(deg, bsum);
    scan_bsum<<<1, 256, 0, stream>>>(bsum, gsum);
    block_scan_write<<<NB, 256, 0, stream>>>(deg, gsum, rowptr, cursor);
    csr_fill<<<N_EDGES / 256, 256, 0, stream>>>(src, dst, cursor, csr_src);

    const int gtiles = (N_NODES + 15) / 16;   // 4 nodes/wave x 4 waves
    // xsum = bf16(feat + gather(feat)) — tiled, XCD-pinned, register-idx
    gather_v5<24, 3><<<gtiles * 8, 256, 0, stream>>>(featbf, rowptr, csr_src, xsum);

    const int gblocks = (N_NODES + 127) / 128;
    // h1 = relu(xsum @ m1a_w + b)          (A tiled24 -> linear out)
    gemm_relu2<KPAD1, 24, 0><<<gblocks, 256, 0, stream>>>(xsum, Wt1, m1ab, h1, nullptr, N_NODES);
    // node1 = relu(h1 @ m1b_w + b), colsum1 fused   (linear A -> tiled32 out)
    gemm_relu2<HID, 0, 32><<<gblocks, 256, 0, stream>>>(h1, Wt2, m1bb, node1, colsum1, N_NODES);
    // y2 = bf16(node1 + gather(node1)) — tiled, XCD-pinned, register-idx
    gather_v5<32, 4><<<gtiles * 8, 256, 0, stream>>>(node1, rowptr, csr_src, y2);
    // h2 = relu(y2 @ m2a_w + b)  (reuse h1 buffer)  (A tiled32 -> linear out)
    gemm_relu2<HID, 32, 0><<<gblocks, 256, 0, stream>>>(y2, Wt3, m2ab, h1, nullptr, N_NODES);
    // node2 = relu(h2 @ m2b_w + b), colsum2 fused   (linear A -> linear out)
    gemm_relu2<HID, 0, 0><<<gblocks, 256, 0, stream>>>(h1, Wt4, m2bb, node2, colsum2, N_NODES);
    // graph head -> gvec = g_last
    graph_head<<<1, 256, 0, stream>>>(colsum0_8, colsum1, colsum2,
                                      g0w, g0b, g1w, g1b, g2w, g2b, glw, glb, gvec);
    // out = node2 + gvec
    final_add<<<((size_t)N_NODES * HID / 4 + 255) / 256, 256, 0, stream>>>(node2, gvec, out);
    (void)in_sizes; (void)n_in; (void)out_size; (void)ws_size;
}